// Round 6
// baseline (417.225 us; speedup 1.0000x reference)
//
#include <hip/hip_runtime.h>
#include <hip/hip_bf16.h>

#define LRELU_ALPHA 0.3f
#define LN_EPS 1e-3f

// ---------------------------------------------------------------------------
// INSTRUMENTATION ROUND on the exact R5 structure: the 6 unmeasured
// dispatches (2x gemm, 2x zero-LDS diversity, ln_mid, ln_head) run their
// bodies REP=4 times (idempotent; outputs bit-identical). Each inflated
// dispatch rises above the 43us harness-fill floor and gets its own rocprof
// row. prep stays un-REP'd (unchanged since R0, est ~12us).
// Solve: dur = G + prep + 4*(g0+g1+d0+d1+lm+lh), G ~= 96 (2 fills + gaps).
// ---------------------------------------------------------------------------
#define REP_G 4
#define REP_D 4
#define REP_L 4

typedef short bf16x8 __attribute__((ext_vector_type(8)));
typedef float f32x4 __attribute__((ext_vector_type(4)));

static __device__ __forceinline__ unsigned short f2bf(float f) {
    union { float f; unsigned u; } v; v.f = f;
    unsigned r = v.u + 0x7fffu + ((v.u >> 16) & 1u);  // RNE
    return (unsigned short)(r >> 16);
}

// async 16B global -> LDS (DMA). LDS dest = wave-uniform base + lane*16.
#define ASYNC_CP16(gsrc, ldst)                                                  \
    __builtin_amdgcn_global_load_lds(                                           \
        (const __attribute__((address_space(1))) unsigned int*)(gsrc),          \
        (__attribute__((address_space(3))) unsigned int*)(ldst), 16, 0, 0)

#define NE 1152      // extended B-rows: 1024 hidden + 15 fused-skinny + pad
#define DIV_P 64     // diversity i-chunk partial slots (4096/DIV_P = 64 i/chunk)
#define DIV_IC (4096 / DIV_P)

// ---------------------------------------------------------------------------
// Fused prep kernel (unchanged R0 structure, not REP'd).
// ---------------------------------------------------------------------------
__global__ void prep_kernel(const float* __restrict__ x,
                            const float* __restrict__ w0a, const float* __restrict__ b0a,
                            const float* __restrict__ w0b, const float* __restrict__ b0b,
                            const float* __restrict__ w1a, const float* __restrict__ b1a,
                            const float* __restrict__ w1b, const float* __restrict__ b1b,
                            unsigned short* __restrict__ x_bf,
                            unsigned short* __restrict__ bT0, unsigned short* __restrict__ bT1,
                            float* __restrict__ be0, float* __restrict__ be1) {
    __shared__ float tile[32][33];
    const int b = blockIdx.x, tid = threadIdx.x;

    if (b < 2048) {                       // ---- cast x ----
        const int i = (b * 256 + tid) * 4;
        const float4 v = *(const float4*)(x + i);
        ushort4 o;
        o.x = f2bf(v.x); o.y = f2bf(v.y); o.z = f2bf(v.z); o.w = f2bf(v.w);
        *(ushort4*)(x_bf + i) = o;
        return;
    }
    if (b < 2560) {                       // ---- transpose w0a -> bT0 ----
        const int b2 = b - 2048;
        const int nb = (b2 & 31) * 32, kb = (b2 >> 5) * 32;
        const int tx = tid & 31, ty = tid >> 5;       // 32 x 8
#pragma unroll
        for (int i = 0; i < 4; ++i)
            tile[ty + i * 8][tx] = w0a[(size_t)(kb + ty + i * 8) * 1024 + nb + tx];
        __syncthreads();
#pragma unroll
        for (int i = 0; i < 4; ++i)
            bT0[(size_t)(nb + ty + i * 8) * 512 + kb + tx] = f2bf(tile[tx][ty + i * 8]);
        return;
    }
    if (b < 3616) {                       // ---- transpose w1a -> bT1 ----
        const int b3 = b - 2560;
        const int nb = (b3 & 31) * 32, kb = (b3 >> 5) * 32;   // kb up to 1055
        const int tx = tid & 31, ty = tid >> 5;
#pragma unroll
        for (int i = 0; i < 4; ++i) {
            const int k = kb + ty + i * 8;
            tile[ty + i * 8][tx] = (k < 1029) ? w1a[(size_t)k * 1024 + nb + tx] : 0.f;
        }
        __syncthreads();
#pragma unroll
        for (int i = 0; i < 4; ++i)
            bT1[(size_t)(nb + ty + i * 8) * 1056 + kb + tx] = f2bf(tile[tx][ty + i * 8]);
        return;
    }
    if (b < 4003) {                       // ---- wcomb 0/1 ----
        const int is1 = (b >= 3745);
        const int b4 = b - (is1 ? 3745 : 3616);
        const int w = tid >> 6, lane = tid & 63;
        const int row = b4 * 4 + w;
        const int F = is1 ? 1029 : 512;
        if (row > F) return;
        const float* wa = is1 ? w1a : w0a;
        const float* ba = is1 ? b1a : b0a;
        const float* wb = is1 ? w1b : w0b;
        const float* bb = is1 ? b1b : b0b;
        const float* src = (row < F) ? (wa + (size_t)row * 1024) : ba;
        float acc[15] = {};
        for (int h = lane; h < 1024; h += 64) {
            const float a = src[h];
            const float* wr = wb + h * 15;
#pragma unroll
            for (int c = 0; c < 15; ++c) acc[c] += a * wr[c];
        }
#pragma unroll
        for (int c = 0; c < 15; ++c)
#pragma unroll
            for (int off = 32; off > 0; off >>= 1) acc[c] += __shfl_xor(acc[c], off, 64);
        if (lane < 15) {
            if (row < F) {
                if (is1) bT1[(size_t)(1024 + lane) * 1056 + row] = f2bf(acc[lane]);
                else     bT0[(size_t)(1024 + lane) * 512  + row] = f2bf(acc[lane]);
            } else {
                if (is1) be1[1024 + lane] = acc[lane] + bb[lane];
                else     be0[1024 + lane] = acc[lane] + bb[lane];
            }
        }
        return;
    }
    {                                     // ---- bias copies ----
        const int b6 = b - 4003;
        if (b6 < 4) be0[b6 * 256 + tid] = b0a[b6 * 256 + tid];
        else        be1[(b6 - 4) * 256 + tid] = b1a[(b6 - 4) * 256 + tid];
    }
}

// ---------------------------------------------------------------------------
// bf16 MFMA GEMM (R5 structure), REP_G-looped. Rep-boundary safe: k-loop's
// final __syncthreads precedes re-staging into As[0]/Bs[0]; epilogue has no
// LDS access; acc reset per rep.
// ---------------------------------------------------------------------------
__global__ __launch_bounds__(256)
void mfma_gemm(const unsigned short* __restrict__ A, int lda,
               const unsigned short* __restrict__ BT, int ldb,
               const float* __restrict__ bias, float* __restrict__ C,
               float* __restrict__ t16, int K) {
    __shared__ unsigned short As[2][64 * 32];
    __shared__ unsigned short Bs[2][64 * 32];
    const int tid = threadIdx.x;
    const int w = tid >> 6, lane = tid & 63;
    const int q = lane >> 4, m16 = lane & 15;
    const int wr = (w >> 1) * 32, wc = (w & 1) * 32;
    const int br = blockIdx.y * 64, bc = blockIdx.x * 64;
    const int sr = tid >> 2, sc = (tid & 3) * 8;

    const unsigned short* gA0 = A + (size_t)(br + sr) * lda + sc;
    const unsigned short* gB0 = BT + (size_t)(bc + sr) * ldb + sc;

    for (int rep = 0; rep < REP_G; ++rep) {
        f32x4 acc[2][2] = {};

        ASYNC_CP16(gA0, &As[0][tid * 8]);
        ASYNC_CP16(gB0, &Bs[0][tid * 8]);
        __syncthreads();

        int cur = 0;
        for (int k0 = 0; k0 < K; k0 += 32) {
            if (k0 + 32 < K) {
                ASYNC_CP16(gA0 + k0 + 32, &As[cur ^ 1][tid * 8]);
                ASYNC_CP16(gB0 + k0 + 32, &Bs[cur ^ 1][tid * 8]);
            }
            bf16x8 af[2], bfr[2];
#pragma unroll
            for (int i = 0; i < 2; ++i)
                af[i] = *(const bf16x8*)(&As[cur][(wr + 16 * i + m16) * 32 + q * 8]);
#pragma unroll
            for (int j = 0; j < 2; ++j)
                bfr[j] = *(const bf16x8*)(&Bs[cur][(wc + 16 * j + m16) * 32 + q * 8]);
#pragma unroll
            for (int i = 0; i < 2; ++i)
#pragma unroll
                for (int j = 0; j < 2; ++j)
                    acc[i][j] = __builtin_amdgcn_mfma_f32_16x16x32_bf16(af[i], bfr[j], acc[i][j], 0, 0, 0);
            __syncthreads();
            cur ^= 1;
        }

#pragma unroll
        for (int i = 0; i < 2; ++i) {
            const int gr = br + wr + 16 * i + q * 4;
#pragma unroll
            for (int j = 0; j < 2; ++j) {
                const int gc = bc + wc + 16 * j + m16;
                if (gc < 1024) {
                    const float b = bias[gc];
#pragma unroll
                    for (int r = 0; r < 4; ++r)
                        C[(size_t)(gr + r) * 1024 + gc] = acc[i][j][r] + b;
                } else if (gc < 1039) {
                    const float b = bias[gc];
#pragma unroll
                    for (int r = 0; r < 4; ++r)
                        t16[(size_t)(gr + r) * 16 + (gc - 1024)] = acc[i][j][r] + b;
                }
            }
        }
    }
}

// ---------------------------------------------------------------------------
// Batch diversity v4 (R5 zero-LDS structure), REP_D-looped. No LDS, no
// barriers; acc reset per rep; stores rewrite identical values.
// ---------------------------------------------------------------------------
__global__ __launch_bounds__(256)
void diversity_kernel(const float* __restrict__ t16, float* __restrict__ dvp, int N) {
    const int j = blockIdx.x * 256 + threadIdx.x;
    const int i0 = blockIdx.y * DIV_IC;

    for (int rep = 0; rep < REP_D; ++rep) {
        // own j-row -> 15 registers (coalesced 64B/lane)
        const f32x4* tj4 = (const f32x4*)(t16 + (size_t)j * 16);
        const f32x4 J0 = tj4[0], J1 = tj4[1], J2 = tj4[2], J3 = tj4[3];
        const float tj_[15] = { J0.x, J0.y, J0.z, J0.w,
                                J1.x, J1.y, J1.z, J1.w,
                                J2.x, J2.y, J2.z, J2.w,
                                J3.x, J3.y, J3.z };

        float acc[5] = {};

        const float* tp = t16 + (size_t)i0 * 16;
#pragma unroll 2
        for (int i = 0; i < DIV_IC; ++i, tp += 16) {
            // wave-uniform loads: broadcast path
            const f32x4 A0 = *(const f32x4*)(tp);
            const f32x4 A1 = *(const f32x4*)(tp + 4);
            const f32x4 A2 = *(const f32x4*)(tp + 8);
            const f32x4 A3 = *(const f32x4*)(tp + 12);   // word 15 unused
            const float ti_[15] = { A0.x, A0.y, A0.z, A0.w,
                                    A1.x, A1.y, A1.z, A1.w,
                                    A2.x, A2.y, A2.z, A2.w,
                                    A3.x, A3.y, A3.z };
#pragma unroll
            for (int k = 0; k < 5; ++k) {
                const float s = fabsf(ti_[3 * k]     - tj_[3 * k])
                              + fabsf(ti_[3 * k + 1] - tj_[3 * k + 1])
                              + fabsf(ti_[3 * k + 2] - tj_[3 * k + 2]);
                acc[k] += __expf(-s);
            }
        }

        float* dst = dvp + ((size_t)blockIdx.y * N + j) * 5;
#pragma unroll
        for (int k = 0; k < 5; ++k) dst[k] = acc[k];
    }
}

// ---------------------------------------------------------------------------
// concat([h, sum(dvp over DIV_P slots)]) -> LN(center) -> LeakyReLU -> bf16
// REP_L-looped with trailing barrier (rs/rs2 reused across reps).
// ---------------------------------------------------------------------------
__global__ void ln_lrelu_mid(const float* __restrict__ h,
                             const float* __restrict__ dv_part,
                             const float* __restrict__ beta,
                             unsigned short* __restrict__ out_bf,
                             int H, int D, int Cp, int M) {
    const int i = blockIdx.x;
    const int tid = threadIdx.x;
    const int C = H + D;
    __shared__ float rs[4], rs2[4];
    const int lane = tid & 63, wave = tid >> 6;

    for (int rep = 0; rep < REP_L; ++rep) {
        float v[5];
        float s = 0.f, s2 = 0.f;
#pragma unroll
        for (int r = 0; r < 5; ++r) {
            const int c = tid + r * 256;
            if (c < C) {
                float x;
                if (c < H) {
                    x = h[(size_t)i * H + c];
                } else {
                    const int k = c - H;
                    x = 0.f;
#pragma unroll 8
                    for (int jc = 0; jc < DIV_P; ++jc)
                        x += dv_part[((size_t)jc * M + i) * D + k];
                }
                v[r] = x; s += x; s2 += x * x;
            }
        }
#pragma unroll
        for (int off = 32; off > 0; off >>= 1) {
            s += __shfl_down(s, off, 64);
            s2 += __shfl_down(s2, off, 64);
        }
        if (lane == 0) { rs[wave] = s; rs2[wave] = s2; }
        __syncthreads();
        const float S = rs[0] + rs[1] + rs[2] + rs[3];
        const float S2 = rs2[0] + rs2[1] + rs2[2] + rs2[3];
        const float mu = S / (float)C;
        const float var = S2 / (float)C - mu * mu;
        const float rstd = rsqrtf(var + LN_EPS);
#pragma unroll
        for (int r = 0; r < 5; ++r) {
            const int c = tid + r * 256;
            if (c < C) {
                float y = (v[r] - mu) * rstd + beta[c];
                y = (y >= 0.f) ? y : LRELU_ALPHA * y;
                out_bf[(size_t)i * Cp + c] = f2bf(y);
            } else if (c < Cp) {
                out_bf[(size_t)i * Cp + c] = 0;  // zero K-pad for next MFMA GEMM
            }
        }
        __syncthreads();                  // rep boundary: rs/rs2 reused
    }
}

// ---------------------------------------------------------------------------
// Final: concat -> LN -> LeakyReLU -> fused head dot. REP_L-looped.
// ---------------------------------------------------------------------------
__global__ void ln_lrelu_head(const float* __restrict__ h,
                              const float* __restrict__ dv_part,
                              const float* __restrict__ beta, const float* __restrict__ wf,
                              const float* __restrict__ bfp, float* __restrict__ out,
                              int H, int D, int M) {
    const int i = blockIdx.x;
    const int tid = threadIdx.x;
    const int C = H + D;
    __shared__ float rs[4], rs2[4], rh[4];
    const int lane = tid & 63, wave = tid >> 6;

    for (int rep = 0; rep < REP_L; ++rep) {
        float v[5];
        float s = 0.f, s2 = 0.f;
#pragma unroll
        for (int r = 0; r < 5; ++r) {
            const int c = tid + r * 256;
            if (c < C) {
                float x;
                if (c < H) {
                    x = h[(size_t)i * H + c];
                } else {
                    const int k = c - H;
                    x = 0.f;
#pragma unroll 8
                    for (int jc = 0; jc < DIV_P; ++jc)
                        x += dv_part[((size_t)jc * M + i) * D + k];
                }
                v[r] = x; s += x; s2 += x * x;
            }
        }
#pragma unroll
        for (int off = 32; off > 0; off >>= 1) {
            s += __shfl_down(s, off, 64);
            s2 += __shfl_down(s2, off, 64);
        }
        if (lane == 0) { rs[wave] = s; rs2[wave] = s2; }
        __syncthreads();
        const float S = rs[0] + rs[1] + rs[2] + rs[3];
        const float S2 = rs2[0] + rs2[1] + rs2[2] + rs2[3];
        const float mu = S / (float)C;
        const float var = S2 / (float)C - mu * mu;
        const float rstd = rsqrtf(var + LN_EPS);
        float hsum = 0.f;
#pragma unroll
        for (int r = 0; r < 5; ++r) {
            const int c = tid + r * 256;
            if (c < C) {
                float y = (v[r] - mu) * rstd + beta[c];
                y = (y >= 0.f) ? y : LRELU_ALPHA * y;
                hsum += y * wf[c];
            }
        }
#pragma unroll
        for (int off = 32; off > 0; off >>= 1) hsum += __shfl_down(hsum, off, 64);
        if (lane == 0) rh[wave] = hsum;
        __syncthreads();
        if (tid == 0) out[i] = rh[0] + rh[1] + rh[2] + rh[3] + bfp[0];
        __syncthreads();                  // rep boundary: rs/rs2/rh reused
    }
}

extern "C" void kernel_launch(void* const* d_in, const int* in_sizes, int n_in,
                              void* d_out, int out_size, void* d_ws, size_t ws_size,
                              hipStream_t stream) {
    const float* x     = (const float*)d_in[0];
    const float* w0a   = (const float*)d_in[1];
    const float* b0a   = (const float*)d_in[2];
    const float* w0b   = (const float*)d_in[3];
    const float* b0b   = (const float*)d_in[4];
    const float* beta0 = (const float*)d_in[5];
    const float* w1a   = (const float*)d_in[6];
    const float* b1a   = (const float*)d_in[7];
    const float* w1b   = (const float*)d_in[8];
    const float* b1b   = (const float*)d_in[9];
    const float* beta1 = (const float*)d_in[10];
    const float* wf    = (const float*)d_in[11];
    const float* bf    = (const float*)d_in[12];
    float* out = (float*)d_out;

    const int M = 4096, NF = 512, HID = 1024, CP = 1056;

    // fp32 workspace (all offsets multiple-of-4 floats -> 16B aligned)
    float* h   = (float*)d_ws;                      // 4096 x 1024
    float* t16 = h   + (size_t)M * HID;             // 4096 x 16 (padded rows)
    float* dvp = t16 + (size_t)M * 16;              // DIV_P x 4096 x 5
    float* be0 = dvp + (size_t)DIV_P * M * 5;       // 1152
    float* be1 = be0 + NE;                          // 1152
    // bf16 workspace (16B-aligned)
    unsigned short* x_bf  = (unsigned short*)(be1 + NE);             // 4096 x 512
    unsigned short* hc_bf = x_bf + (size_t)M * NF;                   // 4096 x 1056
    unsigned short* bT0   = hc_bf + (size_t)M * CP;                  // 1152 x 512
    unsigned short* bT1   = bT0 + (size_t)NE * NF;                   // 1152 x 1056

    // ---- fused prep ----
    prep_kernel<<<4011, 256, 0, stream>>>(x, w0a, b0a, w0b, b0b, w1a, b1a, w1b, b1b,
                                          x_bf, bT0, bT1, be0, be1);

    // ---- layer 0 ----
    mfma_gemm<<<dim3(NE / 64, M / 64), 256, 0, stream>>>(x_bf, NF, bT0, NF, be0, h, t16, NF);
    diversity_kernel<<<dim3(16, DIV_P), 256, 0, stream>>>(t16, dvp, M);
    ln_lrelu_mid<<<M, 256, 0, stream>>>(h, dvp, beta0, hc_bf, HID, 5, CP, M);

    // ---- layer 1 ----
    mfma_gemm<<<dim3(NE / 64, M / 64), 256, 0, stream>>>(hc_bf, CP, bT1, CP, be1, h, t16, CP);
    diversity_kernel<<<dim3(16, DIV_P), 256, 0, stream>>>(t16, dvp, M);
    ln_lrelu_head<<<M, 256, 0, stream>>>(h, dvp, beta1, wf, bf, out, HID, 5, M);
}

// Round 7
// 217.764 us; speedup vs baseline: 1.9159x; 1.9159x over previous
//
#include <hip/hip_runtime.h>
#include <hip/hip_bf16.h>

#define LRELU_ALPHA 0.3f
#define LN_EPS 1e-3f

typedef short bf16x8 __attribute__((ext_vector_type(8)));
typedef float f32x4 __attribute__((ext_vector_type(4)));

static __device__ __forceinline__ unsigned short f2bf(float f) {
    union { float f; unsigned u; } v; v.f = f;
    unsigned r = v.u + 0x7fffu + ((v.u >> 16) & 1u);  // RNE
    return (unsigned short)(r >> 16);
}

// async 16B global -> LDS (DMA). LDS dest = wave-uniform base + lane*16.
#define ASYNC_CP16(gsrc, ldst)                                                  \
    __builtin_amdgcn_global_load_lds(                                           \
        (const __attribute__((address_space(1))) unsigned int*)(gsrc),          \
        (__attribute__((address_space(3))) unsigned int*)(ldst), 16, 0, 0)

#define NE 1152      // extended B-rows: 1024 hidden + 15 fused-skinny + pad
#define DIV_P 64     // diversity i-chunk partial slots (4096/DIV_P = 64 i/chunk)
#define DIV_IC (4096 / DIV_P)

// ---------------------------------------------------------------------------
// Fused prep kernel (unchanged R0 structure).
// ---------------------------------------------------------------------------
__global__ void prep_kernel(const float* __restrict__ x,
                            const float* __restrict__ w0a, const float* __restrict__ b0a,
                            const float* __restrict__ w0b, const float* __restrict__ b0b,
                            const float* __restrict__ w1a, const float* __restrict__ b1a,
                            const float* __restrict__ w1b, const float* __restrict__ b1b,
                            unsigned short* __restrict__ x_bf,
                            unsigned short* __restrict__ bT0, unsigned short* __restrict__ bT1,
                            float* __restrict__ be0, float* __restrict__ be1) {
    __shared__ float tile[32][33];
    const int b = blockIdx.x, tid = threadIdx.x;

    if (b < 2048) {                       // ---- cast x ----
        const int i = (b * 256 + tid) * 4;
        const float4 v = *(const float4*)(x + i);
        ushort4 o;
        o.x = f2bf(v.x); o.y = f2bf(v.y); o.z = f2bf(v.z); o.w = f2bf(v.w);
        *(ushort4*)(x_bf + i) = o;
        return;
    }
    if (b < 2560) {                       // ---- transpose w0a -> bT0 ----
        const int b2 = b - 2048;
        const int nb = (b2 & 31) * 32, kb = (b2 >> 5) * 32;
        const int tx = tid & 31, ty = tid >> 5;       // 32 x 8
#pragma unroll
        for (int i = 0; i < 4; ++i)
            tile[ty + i * 8][tx] = w0a[(size_t)(kb + ty + i * 8) * 1024 + nb + tx];
        __syncthreads();
#pragma unroll
        for (int i = 0; i < 4; ++i)
            bT0[(size_t)(nb + ty + i * 8) * 512 + kb + tx] = f2bf(tile[tx][ty + i * 8]);
        return;
    }
    if (b < 3616) {                       // ---- transpose w1a -> bT1 ----
        const int b3 = b - 2560;
        const int nb = (b3 & 31) * 32, kb = (b3 >> 5) * 32;   // kb up to 1055
        const int tx = tid & 31, ty = tid >> 5;
#pragma unroll
        for (int i = 0; i < 4; ++i) {
            const int k = kb + ty + i * 8;
            tile[ty + i * 8][tx] = (k < 1029) ? w1a[(size_t)k * 1024 + nb + tx] : 0.f;
        }
        __syncthreads();
#pragma unroll
        for (int i = 0; i < 4; ++i)
            bT1[(size_t)(nb + ty + i * 8) * 1056 + kb + tx] = f2bf(tile[tx][ty + i * 8]);
        return;
    }
    if (b < 4003) {                       // ---- wcomb 0/1 ----
        const int is1 = (b >= 3745);
        const int b4 = b - (is1 ? 3745 : 3616);
        const int w = tid >> 6, lane = tid & 63;
        const int row = b4 * 4 + w;
        const int F = is1 ? 1029 : 512;
        if (row > F) return;
        const float* wa = is1 ? w1a : w0a;
        const float* ba = is1 ? b1a : b0a;
        const float* wb = is1 ? w1b : w0b;
        const float* bb = is1 ? b1b : b0b;
        const float* src = (row < F) ? (wa + (size_t)row * 1024) : ba;
        float acc[15] = {};
        for (int h = lane; h < 1024; h += 64) {
            const float a = src[h];
            const float* wr = wb + h * 15;
#pragma unroll
            for (int c = 0; c < 15; ++c) acc[c] += a * wr[c];
        }
#pragma unroll
        for (int c = 0; c < 15; ++c)
#pragma unroll
            for (int off = 32; off > 0; off >>= 1) acc[c] += __shfl_xor(acc[c], off, 64);
        if (lane < 15) {
            if (row < F) {
                if (is1) bT1[(size_t)(1024 + lane) * 1056 + row] = f2bf(acc[lane]);
                else     bT0[(size_t)(1024 + lane) * 512  + row] = f2bf(acc[lane]);
            } else {
                if (is1) be1[1024 + lane] = acc[lane] + bb[lane];
                else     be0[1024 + lane] = acc[lane] + bb[lane];
            }
        }
        return;
    }
    {                                     // ---- bias copies ----
        const int b6 = b - 4003;
        if (b6 < 4) be0[b6 * 256 + tid] = b0a[b6 * 256 + tid];
        else        be1[(b6 - 4) * 256 + tid] = b1a[(b6 - 4) * 256 + tid];
    }
}

// ---------------------------------------------------------------------------
// bf16 MFMA GEMM v3. Two mechanism-backed fixes from R6's counters:
//  (1) XCD-chunk swizzle (T1, bijective, 1152%8==0): HW round-robins flat
//      blockIdx%8 across XCDs; remap so XCD k owns 8 contiguous A-panels x
//      all 18 bx -> per-XCD L2 working set 1.08+2.4MB (fits 4MB), cutting
//      the measured 3.6x over-fetch (39.5MB/rep -> ~28MB).
//  (2) rule-#21 both-sides LDS XOR swizzle: dest stays linear (required by
//      global_load_lds), global SOURCE col pre-swizzled s^((row>>1)&3), and
//      the SAME XOR applied on the ds_read slot -> 2 lanes/bank-group (free)
//      vs measured 9.7M conflict cycles/dispatch.
// ---------------------------------------------------------------------------
__global__ __launch_bounds__(256)
void mfma_gemm(const unsigned short* __restrict__ A, int lda,
               const unsigned short* __restrict__ BT, int ldb,
               const float* __restrict__ bias, float* __restrict__ C,
               float* __restrict__ t16, int K) {
    __shared__ unsigned short As[2][64 * 32];
    __shared__ unsigned short Bs[2][64 * 32];
    const int tid = threadIdx.x;
    const int w = tid >> 6, lane = tid & 63;
    const int q = lane >> 4, m16 = lane & 15;
    const int wr = (w >> 1) * 32, wc = (w & 1) * 32;

    // (1) XCD-chunk swizzle: flat id (x fastest) -> xcd*(1152/8) + flat/8
    const int flat = blockIdx.y * 18 + blockIdx.x;
    const int swz = (flat & 7) * 144 + (flat >> 3);
    const int bx = swz % 18, by = swz / 18;
    const int br = by * 64, bc = bx * 64;

    // (2a) staging: LDS dest linear (tid*16B); global source col XOR-swizzled
    const int sr = tid >> 2;                               // staging row 0..63
    const int scs = (((tid & 3) ^ ((tid >> 3) & 3))) * 8;  // swizzled col (elems)

    const unsigned short* gA0 = A + (size_t)(br + sr) * lda + scs;
    const unsigned short* gB0 = BT + (size_t)(bc + sr) * ldb + scs;

    f32x4 acc[2][2] = {};

    ASYNC_CP16(gA0, &As[0][tid * 8]);
    ASYNC_CP16(gB0, &Bs[0][tid * 8]);
    __syncthreads();

    // (2b) read slot: same XOR keyed by (row>>1)&3 == (m16>>1)&3
    const int qs = (q ^ ((m16 >> 1) & 3)) * 8;

    int cur = 0;
    for (int k0 = 0; k0 < K; k0 += 32) {
        if (k0 + 32 < K) {
            ASYNC_CP16(gA0 + k0 + 32, &As[cur ^ 1][tid * 8]);
            ASYNC_CP16(gB0 + k0 + 32, &Bs[cur ^ 1][tid * 8]);
        }
        bf16x8 af[2], bfr[2];
#pragma unroll
        for (int i = 0; i < 2; ++i)
            af[i] = *(const bf16x8*)(&As[cur][(wr + 16 * i + m16) * 32 + qs]);
#pragma unroll
        for (int j = 0; j < 2; ++j)
            bfr[j] = *(const bf16x8*)(&Bs[cur][(wc + 16 * j + m16) * 32 + qs]);
#pragma unroll
        for (int i = 0; i < 2; ++i)
#pragma unroll
            for (int j = 0; j < 2; ++j)
                acc[i][j] = __builtin_amdgcn_mfma_f32_16x16x32_bf16(af[i], bfr[j], acc[i][j], 0, 0, 0);
        __syncthreads();
        cur ^= 1;
    }

#pragma unroll
    for (int i = 0; i < 2; ++i) {
        const int gr = br + wr + 16 * i + q * 4;
#pragma unroll
        for (int j = 0; j < 2; ++j) {
            const int gc = bc + wc + 16 * j + m16;
            if (gc < 1024) {
                const float b = bias[gc];
#pragma unroll
                for (int r = 0; r < 4; ++r)
                    C[(size_t)(gr + r) * 1024 + gc] = acc[i][j][r] + b;
            } else if (gc < 1039) {
                const float b = bias[gc];
#pragma unroll
                for (int r = 0; r < 4; ++r)
                    t16[(size_t)(gr + r) * 16 + (gc - 1024)] = acc[i][j][r] + b;
            }
        }
    }
}

// ---------------------------------------------------------------------------
// Batch diversity v4 (zero-LDS, symmetric, proven ~6us in R6). One change:
// dvp written TRANSPOSED [j][jc][k] (20B contiguous per (j,jc)) so the LN
// kernels can reduce the 64 partials with one coalesced wave-load instead of
// 5 threads x 64 serial strided loads.
// ---------------------------------------------------------------------------
__global__ __launch_bounds__(256)
void diversity_kernel(const float* __restrict__ t16, float* __restrict__ dvp, int N) {
    const int j = blockIdx.x * 256 + threadIdx.x;
    const int i0 = blockIdx.y * DIV_IC;

    // own j-row -> 15 registers (coalesced 64B/lane)
    const f32x4* tj4 = (const f32x4*)(t16 + (size_t)j * 16);
    const f32x4 J0 = tj4[0], J1 = tj4[1], J2 = tj4[2], J3 = tj4[3];
    const float tj_[15] = { J0.x, J0.y, J0.z, J0.w,
                            J1.x, J1.y, J1.z, J1.w,
                            J2.x, J2.y, J2.z, J2.w,
                            J3.x, J3.y, J3.z };

    float acc[5] = {};

    const float* tp = t16 + (size_t)i0 * 16;
#pragma unroll 2
    for (int i = 0; i < DIV_IC; ++i, tp += 16) {
        // wave-uniform loads: broadcast path
        const f32x4 A0 = *(const f32x4*)(tp);
        const f32x4 A1 = *(const f32x4*)(tp + 4);
        const f32x4 A2 = *(const f32x4*)(tp + 8);
        const f32x4 A3 = *(const f32x4*)(tp + 12);   // word 15 unused
        const float ti_[15] = { A0.x, A0.y, A0.z, A0.w,
                                A1.x, A1.y, A1.z, A1.w,
                                A2.x, A2.y, A2.z, A2.w,
                                A3.x, A3.y, A3.z };
#pragma unroll
        for (int k = 0; k < 5; ++k) {
            const float s = fabsf(ti_[3 * k]     - tj_[3 * k])
                          + fabsf(ti_[3 * k + 1] - tj_[3 * k + 1])
                          + fabsf(ti_[3 * k + 2] - tj_[3 * k + 2]);
            acc[k] += __expf(-s);
        }
    }

    // transposed partial store: [j][jc][k], 20B contiguous per thread
    float* dst = dvp + ((size_t)j * DIV_P + blockIdx.y) * 5;
#pragma unroll
    for (int k = 0; k < 5; ++k) dst[k] = acc[k];
}

// ---------------------------------------------------------------------------
// concat([h, dv(i)]) -> LN(center) -> LeakyReLU -> bf16 (M x Cp)
// dv(i) reduced by wave 0: 64 lanes x 5 contiguous floats (coalesced 1280B)
// + shuffle-reduce, published via LDS.
// ---------------------------------------------------------------------------
__global__ void ln_lrelu_mid(const float* __restrict__ h,
                             const float* __restrict__ dvp,
                             const float* __restrict__ beta,
                             unsigned short* __restrict__ out_bf,
                             int H, int D, int Cp, int M) {
    const int i = blockIdx.x;
    const int tid = threadIdx.x;
    const int C = H + D;
    __shared__ float rs[4], rs2[4], dv5[5];
    const int lane = tid & 63, wave = tid >> 6;

    float v[5];
    float s = 0.f, s2 = 0.f;
#pragma unroll
    for (int r = 0; r < 5; ++r) {
        const int c = tid + r * 256;
        if (c < H) {
            const float x = h[(size_t)i * H + c];
            v[r] = x; s += x; s2 += x * x;
        }
    }
    if (tid < 64) {                       // wave 0: reduce 64 dv partials
        const float* dp = dvp + ((size_t)i * DIV_P + tid) * 5;
        float a0 = dp[0], a1 = dp[1], a2 = dp[2], a3 = dp[3], a4 = dp[4];
#pragma unroll
        for (int off = 32; off > 0; off >>= 1) {
            a0 += __shfl_xor(a0, off, 64);
            a1 += __shfl_xor(a1, off, 64);
            a2 += __shfl_xor(a2, off, 64);
            a3 += __shfl_xor(a3, off, 64);
            a4 += __shfl_xor(a4, off, 64);
        }
        if (tid == 0) { dv5[0] = a0; dv5[1] = a1; dv5[2] = a2; dv5[3] = a3; dv5[4] = a4; }
    }
    __syncthreads();
#pragma unroll
    for (int r = 0; r < 5; ++r) {
        const int c = tid + r * 256;
        if (c >= H && c < C) {
            const float x = dv5[c - H];
            v[r] = x; s += x; s2 += x * x;
        }
    }
#pragma unroll
    for (int off = 32; off > 0; off >>= 1) {
        s += __shfl_down(s, off, 64);
        s2 += __shfl_down(s2, off, 64);
    }
    if (lane == 0) { rs[wave] = s; rs2[wave] = s2; }
    __syncthreads();
    const float S = rs[0] + rs[1] + rs[2] + rs[3];
    const float S2 = rs2[0] + rs2[1] + rs2[2] + rs2[3];
    const float mu = S / (float)C;
    const float var = S2 / (float)C - mu * mu;
    const float rstd = rsqrtf(var + LN_EPS);
#pragma unroll
    for (int r = 0; r < 5; ++r) {
        const int c = tid + r * 256;
        if (c < C) {
            float y = (v[r] - mu) * rstd + beta[c];
            y = (y >= 0.f) ? y : LRELU_ALPHA * y;
            out_bf[(size_t)i * Cp + c] = f2bf(y);
        } else if (c < Cp) {
            out_bf[(size_t)i * Cp + c] = 0;  // zero K-pad for next MFMA GEMM
        }
    }
}

// ---------------------------------------------------------------------------
// Final: concat -> LN -> LeakyReLU -> fused head dot: out[i] = y.wf + bf
// ---------------------------------------------------------------------------
__global__ void ln_lrelu_head(const float* __restrict__ h,
                              const float* __restrict__ dvp,
                              const float* __restrict__ beta, const float* __restrict__ wf,
                              const float* __restrict__ bfp, float* __restrict__ out,
                              int H, int D, int M) {
    const int i = blockIdx.x;
    const int tid = threadIdx.x;
    const int C = H + D;
    __shared__ float rs[4], rs2[4], rh[4], dv5[5];
    const int lane = tid & 63, wave = tid >> 6;

    float v[5];
    float s = 0.f, s2 = 0.f;
#pragma unroll
    for (int r = 0; r < 5; ++r) {
        const int c = tid + r * 256;
        if (c < H) {
            const float x = h[(size_t)i * H + c];
            v[r] = x; s += x; s2 += x * x;
        }
    }
    if (tid < 64) {
        const float* dp = dvp + ((size_t)i * DIV_P + tid) * 5;
        float a0 = dp[0], a1 = dp[1], a2 = dp[2], a3 = dp[3], a4 = dp[4];
#pragma unroll
        for (int off = 32; off > 0; off >>= 1) {
            a0 += __shfl_xor(a0, off, 64);
            a1 += __shfl_xor(a1, off, 64);
            a2 += __shfl_xor(a2, off, 64);
            a3 += __shfl_xor(a3, off, 64);
            a4 += __shfl_xor(a4, off, 64);
        }
        if (tid == 0) { dv5[0] = a0; dv5[1] = a1; dv5[2] = a2; dv5[3] = a3; dv5[4] = a4; }
    }
    __syncthreads();
#pragma unroll
    for (int r = 0; r < 5; ++r) {
        const int c = tid + r * 256;
        if (c >= H && c < C) {
            const float x = dv5[c - H];
            v[r] = x; s += x; s2 += x * x;
        }
    }
#pragma unroll
    for (int off = 32; off > 0; off >>= 1) {
        s += __shfl_down(s, off, 64);
        s2 += __shfl_down(s2, off, 64);
    }
    if (lane == 0) { rs[wave] = s; rs2[wave] = s2; }
    __syncthreads();
    const float S = rs[0] + rs[1] + rs[2] + rs[3];
    const float S2 = rs2[0] + rs2[1] + rs2[2] + rs2[3];
    const float mu = S / (float)C;
    const float var = S2 / (float)C - mu * mu;
    const float rstd = rsqrtf(var + LN_EPS);
    float hsum = 0.f;
#pragma unroll
    for (int r = 0; r < 5; ++r) {
        const int c = tid + r * 256;
        if (c < C) {
            float y = (v[r] - mu) * rstd + beta[c];
            y = (y >= 0.f) ? y : LRELU_ALPHA * y;
            hsum += y * wf[c];
        }
    }
#pragma unroll
    for (int off = 32; off > 0; off >>= 1) hsum += __shfl_down(hsum, off, 64);
    if (lane == 0) rh[wave] = hsum;
    __syncthreads();
    if (tid == 0) out[i] = rh[0] + rh[1] + rh[2] + rh[3] + bfp[0];
}

extern "C" void kernel_launch(void* const* d_in, const int* in_sizes, int n_in,
                              void* d_out, int out_size, void* d_ws, size_t ws_size,
                              hipStream_t stream) {
    const float* x     = (const float*)d_in[0];
    const float* w0a   = (const float*)d_in[1];
    const float* b0a   = (const float*)d_in[2];
    const float* w0b   = (const float*)d_in[3];
    const float* b0b   = (const float*)d_in[4];
    const float* beta0 = (const float*)d_in[5];
    const float* w1a   = (const float*)d_in[6];
    const float* b1a   = (const float*)d_in[7];
    const float* w1b   = (const float*)d_in[8];
    const float* b1b   = (const float*)d_in[9];
    const float* beta1 = (const float*)d_in[10];
    const float* wf    = (const float*)d_in[11];
    const float* bf    = (const float*)d_in[12];
    float* out = (float*)d_out;

    const int M = 4096, NF = 512, HID = 1024, CP = 1056;

    // fp32 workspace (all offsets multiple-of-4 floats -> 16B aligned)
    float* h   = (float*)d_ws;                      // 4096 x 1024
    float* t16 = h   + (size_t)M * HID;             // 4096 x 16 (padded rows)
    float* dvp = t16 + (size_t)M * 16;              // 4096 x DIV_P x 5 (transposed)
    float* be0 = dvp + (size_t)M * DIV_P * 5;       // 1152
    float* be1 = be0 + NE;                          // 1152
    // bf16 workspace (16B-aligned)
    unsigned short* x_bf  = (unsigned short*)(be1 + NE);             // 4096 x 512
    unsigned short* hc_bf = x_bf + (size_t)M * NF;                   // 4096 x 1056
    unsigned short* bT0   = hc_bf + (size_t)M * CP;                  // 1152 x 512
    unsigned short* bT1   = bT0 + (size_t)NE * NF;                   // 1152 x 1056

    // ---- fused prep ----
    prep_kernel<<<4011, 256, 0, stream>>>(x, w0a, b0a, w0b, b0b, w1a, b1a, w1b, b1b,
                                          x_bf, bT0, bT1, be0, be1);

    // ---- layer 0 ----
    mfma_gemm<<<dim3(NE / 64, M / 64), 256, 0, stream>>>(x_bf, NF, bT0, NF, be0, h, t16, NF);
    diversity_kernel<<<dim3(16, DIV_P), 256, 0, stream>>>(t16, dvp, M);
    ln_lrelu_mid<<<M, 256, 0, stream>>>(h, dvp, beta0, hc_bf, HID, 5, CP, M);

    // ---- layer 1 ----
    mfma_gemm<<<dim3(NE / 64, M / 64), 256, 0, stream>>>(hc_bf, CP, bT1, CP, be1, h, t16, CP);
    diversity_kernel<<<dim3(16, DIV_P), 256, 0, stream>>>(t16, dvp, M);
    ln_lrelu_head<<<M, 256, 0, stream>>>(h, dvp, beta1, wf, bf, out, HID, 5, M);
}